// Round 11
// baseline (213.819 us; speedup 1.0000x reference)
//
#include <hip/hip_runtime.h>

// SparseAttention: B=8, M=N=4096, K=64, R=128 nnz/row (uniform CSR, sorted).
// Established (R2-R10): gather is capped by per-CU MSHR*latency (~64 misses x
// ~250cy = 0.26 lines/cy/CU -> 54.6us), invariant to MLP depth (R8/R10 clause)
// and occupancy.  LDS sweeps (R9/R11: 141/121us) lose on VALU machinery.
// R12: L1-WINDOWED GATHER.  Same per-edge gather code as R5-R7, but all 64
//   rows of a block walk the column space in lockstep tiles of 128 cols
//   (one barrier per tile).  Instantaneous K/V working set = 128 cols x 256B
//   = 32KB = L1, contiguous.  Per CU per tile: ~512 K-touches on <=128
//   distinct lines -> ~75% L1 hits -> ~4x fewer MSHR-bound misses.
//   No LDS, no staging, no ballot (group counts via 3 DPP adds).
#define Bc 8
#define Mc 4096
#define Nc 4096
#define Kc 64
#define Rc 128
#define Tcw 128
#define NTW (Nc / Tcw)   // 32 tiles

typedef _Float16 h16;
typedef h16 h16x2 __attribute__((ext_vector_type(2)));
typedef h16 h16x4 __attribute__((ext_vector_type(4)));
typedef h16 h16x8 __attribute__((ext_vector_type(8)));
typedef float f32x4 __attribute__((ext_vector_type(4)));

// DPP cross-lane reduce over the 8-lane group (validated R7/R8/R11):
// xor1=0xB1 (quad_perm), xor2=0x4E (quad_perm), 0x141=row_half_mirror
// (== xor4 once quads are uniform).
template<int CTRL>
__device__ __forceinline__ float dpp_badd(float x) {
    union { float f; int i; } u, r;
    u.f = x;
    r.i = __builtin_amdgcn_update_dpp(0, u.i, CTRL, 0xF, 0xF, true);
    return x + r.f;
}

// fp32 -> fp16 staging for K, V, Q.  XCD-aware: batch b converted by blocks
// with blockIdx&7 == b (same XCD the windowed-gather blocks for b run on).
__global__ __launch_bounds__(256) void cvt_fp16(
    const f32x4* __restrict__ K4, const f32x4* __restrict__ V4,
    const f32x4* __restrict__ Q4,
    h16x4* __restrict__ Kh4, h16x4* __restrict__ Vh4, h16x4* __restrict__ Qh4)
{
    const int nb4   = Nc * Kc / 4;
    const int b     = blockIdx.x & 7;
    const int chunk = blockIdx.x >> 3;
    const int tsel  = chunk >> 8;           // 0:K 1:V 2:Q
    const int idx   = b * nb4 + ((chunk & 255) << 8) + threadIdx.x;
    const f32x4* src = (tsel == 0) ? K4 : (tsel == 1) ? V4 : Q4;
    h16x4*       dst = (tsel == 0) ? Kh4 : (tsel == 1) ? Vh4 : Qh4;
    f32x4 v = __builtin_nontemporal_load(&src[idx]);
    h16x4 o = { (h16)v.x, (h16)v.y, (h16)v.z, (h16)v.w };
    dst[idx] = o;
}

__global__ __launch_bounds__(512, 4) void sattn_win(
    const int* __restrict__ cols,    // [M*R], sorted within row
    const h16* __restrict__ Qh,      // [B,M,K] fp16 (staged)
    const h16* __restrict__ Kh,      // [B,N,K] fp16 (staged)
    const h16* __restrict__ Vh,      // [B,N,K] fp16 (staged)
    float* __restrict__ out)         // [B,M,K] fp32
{
    const int b    = blockIdx.x & 7;         // XCD swizzle: one batch per XCD
    const int rblk = blockIdx.x >> 3;        // 0..63 (64 rows per block)
    const int tid  = threadIdx.x;            // 0..511 (8 waves)
    const int l    = tid & 63;
    const int ln   = tid & 7;                // lane in group; dims ln*8..ln*8+7
    const int gb   = l & 56;                 // group's lane0 within wave
    const int row  = rblk * 64 + (tid >> 3); // one row per 8-lane group

    const h16* Kb = Kh + ((size_t)b * Nc) * Kc;
    const h16* Vb = Vh + ((size_t)b * Nc) * Kc;

    // Q fragment: dims ln*8..ln*8+7 (kept in registers for the whole sweep).
    h16x8 qv = *(const h16x8*)(Qh + (((size_t)b * Mc + row) << 6) + ln * 8);
    h16x2 qh[4];
    #pragma unroll
    for (int j = 0; j < 4; ++j) qh[j] = h16x2{ qv[2 * j], qv[2 * j + 1] };

    const int* crow = cols + row * Rc;

    int   ptr = 0;                           // next unprocessed edge (sorted)
    float m = -1e30f, s = 0.f;
    float acc8[8] = {0.f,0.f,0.f,0.f,0.f,0.f,0.f,0.f};

    for (int t = 0; t < NTW; ++t) {
        const int c_end = (t + 1) * Tcw;

        // process this group's edges with col < c_end (usually one chunk, n<=8)
        for (;;) {
            int  idx   = ptr + ln;
            int  cv    = crow[idx < Rc ? idx : Rc - 1];
            bool valid = (idx < Rc) && (cv < c_end);
            float nf = valid ? 1.f : 0.f;    // group count via DPP (no ballot)
            nf = dpp_badd<0xB1>(nf);
            nf = dpp_badd<0x4E>(nf);
            nf = dpp_badd<0x141>(nf);
            const int n = (int)nf;           // group-uniform
            if (n == 0) break;

            // gather K and V for slots 0..n-1 (masked; loads issued up front)
            int cl8[8]; h16x8 kf[8], vf[8];
            #pragma unroll
            for (int j = 0; j < 8; ++j) if (j < n) {
                cl8[j] = __shfl(cv, gb + j, 64);
                kf[j] = *(const h16x8*)(Kb + (((unsigned)cl8[j]) << 6) + ln * 8);
                vf[j] = *(const h16x8*)(Vb + (((unsigned)cl8[j]) << 6) + ln * 8);
            }

            // SDDMM dots + DPP group reduce -> group-uniform logits
            float lg[8];
            #pragma unroll
            for (int j = 0; j < 8; ++j) if (j < n) {
                float a = 0.f;
                #pragma unroll
                for (int d2 = 0; d2 < 4; ++d2) {
                    h16x2 kj = { kf[j][2 * d2], kf[j][2 * d2 + 1] };
#if defined(__has_builtin)
#if __has_builtin(__builtin_amdgcn_fdot2)
                    a = __builtin_amdgcn_fdot2(qh[d2], kj, a, false);
#else
                    a += (float)qh[d2].x * (float)kj.x + (float)qh[d2].y * (float)kj.y;
#endif
#else
                    a += (float)qh[d2].x * (float)kj.x + (float)qh[d2].y * (float)kj.y;
#endif
                }
                a = dpp_badd<0xB1>(a);
                a = dpp_badd<0x4E>(a);
                a = dpp_badd<0x141>(a);
                lg[j] = a;
            }

            // online softmax: one rescale per chunk (validated R11 math)
            float cm = -1e30f;
            #pragma unroll
            for (int j = 0; j < 8; ++j) if (j < n) cm = fmaxf(cm, lg[j]);
            if (cm > m) {
                float sc = __expf(m - cm);
                s *= sc;
                #pragma unroll
                for (int d2 = 0; d2 < 8; ++d2) acc8[d2] *= sc;
                m = cm;
            }
            #pragma unroll
            for (int j = 0; j < 8; ++j) if (j < n) {
                float wj = __expf(lg[j] - m);
                s += wj;
                #pragma unroll
                for (int d2 = 0; d2 < 8; ++d2)
                    acc8[d2] = fmaf((float)vf[j][d2], wj, acc8[d2]);
            }

            ptr += n;
            if (n < 8) break;                // sorted -> this tile exhausted
        }

        // hold every group of the block on the same 32-KB L1 column window
        __syncthreads();
    }

    // epilogue: group holds the complete row (8 lanes x 8 dims)
    const float inv = 1.0f / s;
    float* orow = out + (((size_t)b * Mc + row) << 6) + ln * 8;
    *(f32x4*)orow       = f32x4{acc8[0]*inv, acc8[1]*inv, acc8[2]*inv, acc8[3]*inv};
    *((f32x4*)orow + 1) = f32x4{acc8[4]*inv, acc8[5]*inv, acc8[6]*inv, acc8[7]*inv};
}

extern "C" void kernel_launch(void* const* d_in, const int* in_sizes, int n_in,
                              void* d_out, int out_size, void* d_ws, size_t ws_size,
                              hipStream_t stream) {
    // inputs: 0 row_indices, 1 row_offsets, 2 column_indices, 3 q3d, 4 k3d, 5 v3d, 6 values
    const int*   cols = (const int*)d_in[2];
    const float* Qm   = (const float*)d_in[3];
    const float* Km   = (const float*)d_in[4];
    const float* Vm   = (const float*)d_in[5];
    float* out = (float*)d_out;

    h16* Kh = (h16*)d_ws;
    h16* Vh = Kh + (size_t)Bc * Nc * Kc;
    h16* Qh = Vh + (size_t)Bc * Nc * Kc;   // 3 x 4.19 MB = 12.6 MB in d_ws

    cvt_fp16<<<dim3(Bc * 3 * 256), dim3(256), 0, stream>>>(
        (const f32x4*)Km, (const f32x4*)Vm, (const f32x4*)Qm,
        (h16x4*)Kh, (h16x4*)Vh, (h16x4*)Qh);

    // 512 blocks = 8 batches x 64 row-blocks (64 rows each); 2 blocks/CU.
    sattn_win<<<dim3(Bc * Mc / 64), dim3(512), 0, stream>>>(
        cols, Qh, Kh, Vh, out);
}

// Round 12
// 140.412 us; speedup vs baseline: 1.5228x; 1.5228x over previous
//
#include <hip/hip_runtime.h>

// SparseAttention: B=8, M=N=4096, K=64, R=128 nnz/row (uniform CSR).
// FINAL STRUCTURE (R7, best measured: dur 138.0us, sattn 53.1us).
// Established roofline model (R2-R12): the random K/V gather is bound by the
// per-CU line-delivery rate ~0.26 lines/cy/CU (~33 B/cy/CU, L2-resident,
// FETCH shows inputs read from HBM once).  Invariant to occupancy (33-72%),
// stream depth (5-16, HW-pinned via asm clause in R8/R10), and scheduling.
// Alternatives measured and rejected: LDS sweeps 121-141us (VALU machinery),
// L1-windowed gather 129us (machinery + killed MLP), nt/sc0 58us (L2 thrash).
// R13 = R7 exactly, minus Q staging (Q converted f32->fp16 in-kernel, same
// rounding as the staged path; cuts cvt kernel work by 1/3).
#define Bc 8
#define Mc 4096
#define Nc 4096
#define Kc 64
#define Rc 128

typedef _Float16 h16;
typedef h16 h16x2 __attribute__((ext_vector_type(2)));
typedef h16 h16x4 __attribute__((ext_vector_type(4)));
typedef h16 h16x8 __attribute__((ext_vector_type(8)));
typedef float f32x4 __attribute__((ext_vector_type(4)));
typedef int   i32x4 __attribute__((ext_vector_type(4)));

// DPP cross-lane reduce helpers (VALU, no DS pipe).
// XOR1 = quad_perm[1,0,3,2]=0xB1, XOR2 = quad_perm[2,3,0,1]=0x4E,
// MIR  = row_half_mirror=0x141 (== xor4 once each quad is uniform),
// ROR8 = row_ror:8=0x128 (exact xor8 within a 16-lane row).
template<int CTRL>
__device__ __forceinline__ float dpp_badd(float x) {
    union { float f; int i; } u, r;
    u.f = x;
    r.i = __builtin_amdgcn_update_dpp(0, u.i, CTRL, 0xF, 0xF, true);
    return x + r.f;
}
template<int CTRL>
__device__ __forceinline__ float dpp_bmax(float x) {
    union { float f; int i; } u, r;
    u.f = x;
    r.i = __builtin_amdgcn_update_dpp(0, u.i, CTRL, 0xF, 0xF, true);
    return fmaxf(x, r.f);
}

// fp32 -> fp16 staging for K and V only.  XCD-aware: batch b converted by
// blocks with blockIdx&7 == b (same XCD that sattn's batch-b gathers run on).
__global__ __launch_bounds__(256) void cvt_fp16(
    const f32x4* __restrict__ K4, const f32x4* __restrict__ V4,
    h16x4* __restrict__ Kh4, h16x4* __restrict__ Vh4)
{
    const int nb4   = Nc * Kc / 4;          // 65536 f32x4 per tensor per batch
    const int b     = blockIdx.x & 7;       // XCD == batch
    const int chunk = blockIdx.x >> 3;      // 0..511
    const int tsel  = chunk >> 8;           // 0:K 1:V (256 blocks each)
    const int idx   = b * nb4 + ((chunk & 255) << 8) + threadIdx.x;
    const f32x4* src = (tsel == 0) ? K4 : V4;
    h16x4*       dst = (tsel == 0) ? Kh4 : Vh4;
    f32x4 v = __builtin_nontemporal_load(&src[idx]);
    h16x4 o = { (h16)v.x, (h16)v.y, (h16)v.z, (h16)v.w };
    dst[idx] = o;
}

__global__ __launch_bounds__(256, 4) void sattn_kernel(
    const int* __restrict__ cols,    // [M*R], sorted within row
    const float* __restrict__ Q,     // [B,M,K] fp32 (converted in-kernel)
    const h16* __restrict__ Kh,      // [B,N,K] fp16 (staged)
    const h16* __restrict__ Vh,      // [B,N,K] fp16 (staged)
    float* __restrict__ out)         // [B,M,K] fp32
{
    const int b    = blockIdx.x & 7;          // XCD swizzle: one batch per XCD L2
    const int rb   = blockIdx.x >> 3;         // row-pair index within batch
    const int w    = threadIdx.x >> 6;        // wave 0..3
    const int rw   = w >> 1;                  // row-in-block 0/1
    const int half = w & 1;                   // which 64 of the row's 128 edges
    const int row  = rb * 2 + rw;
    const int l    = threadIdx.x & 63;
    const int g    = l >> 3;                  // group 0..7
    const int ln   = l & 7;                   // lane-in-group; dims ln*8..ln*8+7

    __shared__ float s_m[2][2];               // per-row per-half max
    __shared__ float s_s[2][2];               // per-row per-half expsum
    __shared__ __align__(16) float s_part[2][64]; // half-1 partial out

    const h16* Kb = Kh + ((size_t)b * Nc) * Kc;
    const h16* Vb = Vh + ((size_t)b * Nc) * Kc;

    // Q fragment: 8 f32 at dim ln*8 (wave reads the same 256B row -> L1-hot),
    // converted to fp16 here (identical rounding to the staged path).
    const f32x4* qp = (const f32x4*)(Q + (((size_t)b * Mc + row) << 6) + ln * 8);
    f32x4 q0 = qp[0], q1 = qp[1];
    h16x2 qh[4];
    qh[0] = h16x2{ (h16)q0.x, (h16)q0.y };
    qh[1] = h16x2{ (h16)q0.z, (h16)q0.w };
    qh[2] = h16x2{ (h16)q1.x, (h16)q1.y };
    qh[3] = h16x2{ (h16)q1.z, (h16)q1.w };

    // This group's 8 CONTIGUOUS edges: e = half*64 + g*8 + p.
    // Two int4 loads, same 32B for all 8 lanes of the group -> L1 broadcast.
    const int* crow = cols + row * Rc + half * 64 + g * 8;
    i32x4 c0 = *(const i32x4*)crow;
    i32x4 c1 = *(const i32x4*)(crow + 4);
    int col8[8] = { c0[0], c0[1], c0[2], c0[3], c1[0], c1[1], c1[2], c1[3] };

    // ---- Issue ALL 16 gathers back-to-back: 8 K then 8 V. ----
    h16x8 kv[8];
    #pragma unroll
    for (int p = 0; p < 8; ++p)
        kv[p] = *(const h16x8*)(Kb + (((unsigned)col8[p]) << 6) + ln * 8);
    h16x8 vv[8];
    #pragma unroll
    for (int p = 0; p < 8; ++p)
        vv[p] = *(const h16x8*)(Vb + (((unsigned)col8[p]) << 6) + ln * 8);
    __builtin_amdgcn_sched_barrier(0);

    // ---- SDDMM dots (fp16 fdot2) + DPP group reduce (masks 1,2,4) ----
    float lg[8];
    #pragma unroll
    for (int p = 0; p < 8; ++p) {
        float acc = 0.f;
        #pragma unroll
        for (int j = 0; j < 4; ++j) {
            h16x2 kj = { kv[p][2 * j], kv[p][2 * j + 1] };
#if defined(__has_builtin)
#if __has_builtin(__builtin_amdgcn_fdot2)
            acc = __builtin_amdgcn_fdot2(qh[j], kj, acc, false);
#else
            acc += (float)qh[j].x * (float)kj.x + (float)qh[j].y * (float)kj.y;
#endif
#else
            acc += (float)qh[j].x * (float)kj.x + (float)qh[j].y * (float)kj.y;
#endif
        }
        acc = dpp_badd<0xB1>(acc);    // xor1
        acc = dpp_badd<0x4E>(acc);    // xor2
        acc = dpp_badd<0x141>(acc);   // xor4 (row_half_mirror, quad-uniform)
        lg[p] = acc;                  // logit of edge half*64+g*8+p (all 8 lanes)
    }

    // ---- softmax: local (64-edge) max, cross-wave exchange, exp, sum ----
    float m = lg[0];
    #pragma unroll
    for (int p = 1; p < 8; ++p) m = fmaxf(m, lg[p]);
    m = dpp_bmax<0x128>(m);                    // xor8 (row_ror:8)
    m = fmaxf(m, __shfl_xor(m, 16, 64));
    m = fmaxf(m, __shfl_xor(m, 32, 64));
    if (l == 0) s_m[rw][half] = m;
    __syncthreads();
    m = fmaxf(s_m[rw][0], s_m[rw][1]);

    float s = 0.f;
    #pragma unroll
    for (int p = 0; p < 8; ++p) { lg[p] = __expf(lg[p] - m); s += lg[p]; }
    s = dpp_badd<0x128>(s);                    // xor8
    s += __shfl_xor(s, 16, 64);
    s += __shfl_xor(s, 32, 64);
    if (l == 0) s_s[rw][half] = s;

    // ---- SPMM over this wave's 64 edges (V already in registers) ----
    float acc8[8] = {0.f, 0.f, 0.f, 0.f, 0.f, 0.f, 0.f, 0.f};
    #pragma unroll
    for (int p = 0; p < 8; ++p) {
        const float wp = lg[p];
        #pragma unroll
        for (int j = 0; j < 8; ++j)
            acc8[j] = fmaf((float)vv[p][j], wp, acc8[j]);   // v_fma_mix
    }
    // cross-group reduce: DPP xor8, then shfl 16/32
    #pragma unroll
    for (int j = 0; j < 8; ++j) {
        acc8[j] = dpp_badd<0x128>(acc8[j]);
        acc8[j] += __shfl_xor(acc8[j], 16, 64);
        acc8[j] += __shfl_xor(acc8[j], 32, 64);
    }

    // half-1 publishes its partial (8 lanes x 32B, conflict-free)
    if (half == 1 && g == 0) {
        *(f32x4*)&s_part[rw][ln * 8]     = f32x4{acc8[0], acc8[1], acc8[2], acc8[3]};
        *(f32x4*)&s_part[rw][ln * 8 + 4] = f32x4{acc8[4], acc8[5], acc8[6], acc8[7]};
    }
    __syncthreads();

    if (half == 0 && g == 0) {
        const float inv = 1.0f / (s_s[rw][0] + s_s[rw][1]);
        const float* pp = &s_part[rw][ln * 8];
        float* orow = out + (((size_t)b * Mc + row) << 6) + ln * 8;
        f32x4 o0 = { (acc8[0] + pp[0]) * inv, (acc8[1] + pp[1]) * inv,
                     (acc8[2] + pp[2]) * inv, (acc8[3] + pp[3]) * inv };
        f32x4 o1 = { (acc8[4] + pp[4]) * inv, (acc8[5] + pp[5]) * inv,
                     (acc8[6] + pp[6]) * inv, (acc8[7] + pp[7]) * inv };
        __builtin_nontemporal_store(o0, (f32x4*)orow);
        __builtin_nontemporal_store(o1, (f32x4*)orow + 1);
    }
}

extern "C" void kernel_launch(void* const* d_in, const int* in_sizes, int n_in,
                              void* d_out, int out_size, void* d_ws, size_t ws_size,
                              hipStream_t stream) {
    // inputs: 0 row_indices, 1 row_offsets, 2 column_indices, 3 q3d, 4 k3d, 5 v3d, 6 values
    const int*   cols = (const int*)d_in[2];
    const float* Qm   = (const float*)d_in[3];
    const float* Km   = (const float*)d_in[4];
    const float* Vm   = (const float*)d_in[5];
    float* out = (float*)d_out;

    h16* Kh = (h16*)d_ws;
    h16* Vh = Kh + (size_t)Bc * Nc * Kc;   // 2 x 4.19 MB in d_ws

    cvt_fp16<<<dim3(Bc * 2 * 256), dim3(256), 0, stream>>>(
        (const f32x4*)Km, (const f32x4*)Vm, (h16x4*)Kh, (h16x4*)Vh);

    sattn_kernel<<<dim3(Bc * Mc / 2), dim3(256), 0, stream>>>(cols, Qm, Kh, Vh, out);
}

// Round 13
// 138.955 us; speedup vs baseline: 1.5388x; 1.0105x over previous
//
#include <hip/hip_runtime.h>

// SparseAttention: B=8, M=N=4096, K=64, R=128 nnz/row (uniform CSR).
// FINAL KERNEL = R7 structure (best measured: total 138.0us, sattn 53.1us).
// Roofline model (closed over R2-R13): the random K/V gather is bound by the
// per-CU random-line delivery rate ~0.26 lines/cy/CU (~33 B/cy/CU).  Time =
// 8.39M lines / rate = ~54us; measured 53-58 across every gather variant --
// occupancy 33-72%, stream depth 5-16 (HW-pinned asm clause, R8/R10),
// DPP vs shfl, sched_barrier, cache modifiers.  fp16 staging halved traffic
// (126->63us).  Rejected alternatives (measured): LDS sweeps 121/141us (VALU
// machinery), L1-windowed gather 129us, nt/sc0 58us (L2 thrash), in-kernel
// Q cvt 57.4us (R13: doubled Q stream).  Dense-masked MFMA priced ~70us.
#define Bc 8
#define Mc 4096
#define Nc 4096
#define Kc 64
#define Rc 128

typedef _Float16 h16;
typedef h16 h16x2 __attribute__((ext_vector_type(2)));
typedef h16 h16x4 __attribute__((ext_vector_type(4)));
typedef h16 h16x8 __attribute__((ext_vector_type(8)));
typedef float f32x4 __attribute__((ext_vector_type(4)));
typedef int   i32x4 __attribute__((ext_vector_type(4)));

// DPP cross-lane reduce helpers (VALU, no DS pipe).
// XOR1 = quad_perm[1,0,3,2]=0xB1, XOR2 = quad_perm[2,3,0,1]=0x4E,
// MIR  = row_half_mirror=0x141 (== xor4 once each quad is uniform),
// ROR8 = row_ror:8=0x128 (exact xor8 within a 16-lane row).
template<int CTRL>
__device__ __forceinline__ float dpp_badd(float x) {
    union { float f; int i; } u, r;
    u.f = x;
    r.i = __builtin_amdgcn_update_dpp(0, u.i, CTRL, 0xF, 0xF, true);
    return x + r.f;
}
template<int CTRL>
__device__ __forceinline__ float dpp_bmax(float x) {
    union { float f; int i; } u, r;
    u.f = x;
    r.i = __builtin_amdgcn_update_dpp(0, u.i, CTRL, 0xF, 0xF, true);
    return fmaxf(x, r.f);
}

// fp32 -> fp16 staging for K, V, Q.  XCD-aware: batch b converted by blocks
// with blockIdx&7 == b (same XCD that sattn's batch-b gathers run on).
__global__ __launch_bounds__(256) void cvt_fp16(
    const f32x4* __restrict__ K4, const f32x4* __restrict__ V4,
    const f32x4* __restrict__ Q4,
    h16x4* __restrict__ Kh4, h16x4* __restrict__ Vh4, h16x4* __restrict__ Qh4)
{
    const int nb4   = Nc * Kc / 4;          // 65536 f32x4 per tensor per batch
    const int b     = blockIdx.x & 7;       // XCD == batch
    const int chunk = blockIdx.x >> 3;      // 0..767
    const int tsel  = chunk >> 8;           // 0:K 1:V 2:Q (256 blocks each)
    const int idx   = b * nb4 + ((chunk & 255) << 8) + threadIdx.x;
    const f32x4* src = (tsel == 0) ? K4 : (tsel == 1) ? V4 : Q4;
    h16x4*       dst = (tsel == 0) ? Kh4 : (tsel == 1) ? Vh4 : Qh4;
    f32x4 v = __builtin_nontemporal_load(&src[idx]);
    h16x4 o = { (h16)v.x, (h16)v.y, (h16)v.z, (h16)v.w };
    dst[idx] = o;
}

__global__ __launch_bounds__(256, 4) void sattn_kernel(
    const int* __restrict__ cols,    // [M*R], sorted within row
    const h16* __restrict__ Qh,      // [B,M,K] fp16 (staged)
    const h16* __restrict__ Kh,      // [B,N,K] fp16 (staged)
    const h16* __restrict__ Vh,      // [B,N,K] fp16 (staged)
    float* __restrict__ out)         // [B,M,K] fp32
{
    const int b    = blockIdx.x & 7;          // XCD swizzle: one batch per XCD L2
    const int rb   = blockIdx.x >> 3;         // row-pair index within batch
    const int w    = threadIdx.x >> 6;        // wave 0..3
    const int rw   = w >> 1;                  // row-in-block 0/1
    const int half = w & 1;                   // which 64 of the row's 128 edges
    const int row  = rb * 2 + rw;
    const int l    = threadIdx.x & 63;
    const int g    = l >> 3;                  // group 0..7
    const int ln   = l & 7;                   // lane-in-group; dims ln*8..ln*8+7

    __shared__ float s_m[2][2];               // per-row per-half max
    __shared__ float s_s[2][2];               // per-row per-half expsum
    __shared__ __align__(16) float s_part[2][64]; // half-1 partial out

    const h16* Kb = Kh + ((size_t)b * Nc) * Kc;
    const h16* Vb = Vh + ((size_t)b * Nc) * Kc;

    // Q fragment (16B at dim ln*8); identical across the 8 groups -> broadcast.
    h16x8 qv = *(const h16x8*)(Qh + (((size_t)b * Mc + row) << 6) + ln * 8);
    h16x2 qh[4];
    #pragma unroll
    for (int j = 0; j < 4; ++j) qh[j] = h16x2{ qv[2 * j], qv[2 * j + 1] };

    // This group's 8 CONTIGUOUS edges: e = half*64 + g*8 + p.
    // Two int4 loads, same 32B for all 8 lanes of the group -> L1 broadcast.
    const int* crow = cols + row * Rc + half * 64 + g * 8;
    i32x4 c0 = *(const i32x4*)crow;
    i32x4 c1 = *(const i32x4*)(crow + 4);
    int col8[8] = { c0[0], c0[1], c0[2], c0[3], c1[0], c1[1], c1[2], c1[3] };

    // ---- Issue ALL 16 gathers back-to-back: 8 K then 8 V. ----
    h16x8 kv[8];
    #pragma unroll
    for (int p = 0; p < 8; ++p)
        kv[p] = *(const h16x8*)(Kb + (((unsigned)col8[p]) << 6) + ln * 8);
    h16x8 vv[8];
    #pragma unroll
    for (int p = 0; p < 8; ++p)
        vv[p] = *(const h16x8*)(Vb + (((unsigned)col8[p]) << 6) + ln * 8);
    __builtin_amdgcn_sched_barrier(0);

    // ---- SDDMM dots (fp16 fdot2) + DPP group reduce (masks 1,2,4) ----
    float lg[8];
    #pragma unroll
    for (int p = 0; p < 8; ++p) {
        float acc = 0.f;
        #pragma unroll
        for (int j = 0; j < 4; ++j) {
            h16x2 kj = { kv[p][2 * j], kv[p][2 * j + 1] };
#if defined(__has_builtin)
#if __has_builtin(__builtin_amdgcn_fdot2)
            acc = __builtin_amdgcn_fdot2(qh[j], kj, acc, false);
#else
            acc += (float)qh[j].x * (float)kj.x + (float)qh[j].y * (float)kj.y;
#endif
#else
            acc += (float)qh[j].x * (float)kj.x + (float)qh[j].y * (float)kj.y;
#endif
        }
        acc = dpp_badd<0xB1>(acc);    // xor1
        acc = dpp_badd<0x4E>(acc);    // xor2
        acc = dpp_badd<0x141>(acc);   // xor4 (row_half_mirror, quad-uniform)
        lg[p] = acc;                  // logit of edge half*64+g*8+p (all 8 lanes)
    }

    // ---- softmax: local (64-edge) max, cross-wave exchange, exp, sum ----
    float m = lg[0];
    #pragma unroll
    for (int p = 1; p < 8; ++p) m = fmaxf(m, lg[p]);
    m = dpp_bmax<0x128>(m);                    // xor8 (row_ror:8)
    m = fmaxf(m, __shfl_xor(m, 16, 64));
    m = fmaxf(m, __shfl_xor(m, 32, 64));
    if (l == 0) s_m[rw][half] = m;
    __syncthreads();
    m = fmaxf(s_m[rw][0], s_m[rw][1]);

    float s = 0.f;
    #pragma unroll
    for (int p = 0; p < 8; ++p) { lg[p] = __expf(lg[p] - m); s += lg[p]; }
    s = dpp_badd<0x128>(s);                    // xor8
    s += __shfl_xor(s, 16, 64);
    s += __shfl_xor(s, 32, 64);
    if (l == 0) s_s[rw][half] = s;

    // ---- SPMM over this wave's 64 edges (V already in registers) ----
    float acc8[8] = {0.f, 0.f, 0.f, 0.f, 0.f, 0.f, 0.f, 0.f};
    #pragma unroll
    for (int p = 0; p < 8; ++p) {
        const float wp = lg[p];
        #pragma unroll
        for (int j = 0; j < 8; ++j)
            acc8[j] = fmaf((float)vv[p][j], wp, acc8[j]);   // v_fma_mix
    }
    // cross-group reduce: DPP xor8, then shfl 16/32
    #pragma unroll
    for (int j = 0; j < 8; ++j) {
        acc8[j] = dpp_badd<0x128>(acc8[j]);
        acc8[j] += __shfl_xor(acc8[j], 16, 64);
        acc8[j] += __shfl_xor(acc8[j], 32, 64);
    }

    // half-1 publishes its partial (8 lanes x 32B, conflict-free)
    if (half == 1 && g == 0) {
        *(f32x4*)&s_part[rw][ln * 8]     = f32x4{acc8[0], acc8[1], acc8[2], acc8[3]};
        *(f32x4*)&s_part[rw][ln * 8 + 4] = f32x4{acc8[4], acc8[5], acc8[6], acc8[7]};
    }
    __syncthreads();

    if (half == 0 && g == 0) {
        const float inv = 1.0f / (s_s[rw][0] + s_s[rw][1]);
        const float* pp = &s_part[rw][ln * 8];
        float* orow = out + (((size_t)b * Mc + row) << 6) + ln * 8;
        f32x4 o0 = { (acc8[0] + pp[0]) * inv, (acc8[1] + pp[1]) * inv,
                     (acc8[2] + pp[2]) * inv, (acc8[3] + pp[3]) * inv };
        f32x4 o1 = { (acc8[4] + pp[4]) * inv, (acc8[5] + pp[5]) * inv,
                     (acc8[6] + pp[6]) * inv, (acc8[7] + pp[7]) * inv };
        __builtin_nontemporal_store(o0, (f32x4*)orow);
        __builtin_nontemporal_store(o1, (f32x4*)orow + 1);
    }
}

extern "C" void kernel_launch(void* const* d_in, const int* in_sizes, int n_in,
                              void* d_out, int out_size, void* d_ws, size_t ws_size,
                              hipStream_t stream) {
    // inputs: 0 row_indices, 1 row_offsets, 2 column_indices, 3 q3d, 4 k3d, 5 v3d, 6 values
    const int*   cols = (const int*)d_in[2];
    const float* Qm   = (const float*)d_in[3];
    const float* Km   = (const float*)d_in[4];
    const float* Vm   = (const float*)d_in[5];
    float* out = (float*)d_out;

    h16* Kh = (h16*)d_ws;
    h16* Vh = Kh + (size_t)Bc * Nc * Kc;
    h16* Qh = Vh + (size_t)Bc * Nc * Kc;   // 3 x 4.19 MB = 12.6 MB in d_ws

    cvt_fp16<<<dim3(Bc * 3 * 256), dim3(256), 0, stream>>>(
        (const f32x4*)Km, (const f32x4*)Vm, (const f32x4*)Qm,
        (h16x4*)Kh, (h16x4*)Vh, (h16x4*)Qh);

    sattn_kernel<<<dim3(Bc * Mc / 2), dim3(256), 0, stream>>>(cols, Qh, Kh, Vh, out);
}